// Round 7
// baseline (516.046 us; speedup 1.0000x reference)
//
#include <hip/hip_runtime.h>
#include <stdint.h>

#define NE 50000   // entities
#define DD 128     // dim
#define RR 16      // relations
#define EE 50000   // edges per relation
#define NT 64      // node tile per block
#define NTOT (RR * NE)        // 800000 (node,rel) keys, node-major
#define CAP 8                 // bucket capacity: one 64B line per key
#define OVCAP 65536           // overflow capacity (expect ~1 entry)

typedef short  shortx8 __attribute__((ext_vector_type(8)));
typedef short  shortx4 __attribute__((ext_vector_type(4)));
typedef float  floatx4 __attribute__((ext_vector_type(4)));

__device__ __forceinline__ unsigned short f2bf(float f) {
    unsigned u = __float_as_uint(f);
    u += 0x7fffu + ((u >> 16) & 1u);   // RNE
    return (unsigned short)(u >> 16);
}
__device__ __forceinline__ float bf2f(unsigned short h) {
    return __uint_as_float(((unsigned)h) << 16);
}

// ---- single preprocessing kernel:
//  seg T: rel_trans -> MFMA-fragment-ordered bf16 Tf
//  seg E: ent_emb fp32 -> bf16
//  seg F: edges -> buckets edges[key*8+rank] via atomic rank; overflow -> ovf list
// Tf: element T[r][row][k] at ((((r*8+(row>>4))*4+(k>>5))*64) + ((k>>3)&3)*16 + (row&15))*8 + (k&7)
#define TB 128
#define EB 6250
#define FB 782
__global__ void prep_k(const float* __restrict__ rt, unsigned short* __restrict__ Tf,
                       const float4* __restrict__ emb, shortx4* __restrict__ embA,
                       const int* __restrict__ erow, const int* __restrict__ ecol,
                       const float* __restrict__ eval,
                       int* __restrict__ counts, int* __restrict__ ovfh,
                       int4* __restrict__ ovf, int2* __restrict__ edges) {
    int b = blockIdx.x, t = threadIdx.x;
    if (b < TB) {
        int c = b * 256 + t;                 // chunk: 8 consecutive k of one (r,row)
        int r = c >> 11, row = (c >> 4) & 127, cb = c & 15;
        int kt = cb >> 2, qq = cb & 3, rg = row >> 4, m = row & 15;
        const float4* src = (const float4*)(rt + (size_t)c * 8);
        float4 v0 = src[0], v1 = src[1];
        shortx8 w;
        w[0] = (short)f2bf(v0.x); w[1] = (short)f2bf(v0.y);
        w[2] = (short)f2bf(v0.z); w[3] = (short)f2bf(v0.w);
        w[4] = (short)f2bf(v1.x); w[5] = (short)f2bf(v1.y);
        w[6] = (short)f2bf(v1.z); w[7] = (short)f2bf(v1.w);
        size_t idx = ((((size_t)r * 8 + rg) * 4 + kt) * 64 + qq * 16 + m) * 8;
        *(shortx8*)(Tf + idx) = w;
    } else if (b < TB + EB) {
        int i = (b - TB) * 256 + t;
        if (i < NE * DD / 4) {
            float4 v = emb[i];
            shortx4 w;
            w[0] = (short)f2bf(v.x); w[1] = (short)f2bf(v.y);
            w[2] = (short)f2bf(v.z); w[3] = (short)f2bf(v.w);
            embA[i] = w;
        }
    } else {
        int e4 = (b - TB - EB) * 256 + t;
        if (e4 < RR * EE / 4) {
            int r  = e4 / (EE / 4);
            int i4 = e4 - r * (EE / 4);
            int4   rw = *(const int4*)(erow + (size_t)r * EE + i4 * 4);
            int4   cl = *(const int4*)(ecol + (size_t)r * EE + i4 * 4);
            float4 vl = *(const float4*)(eval + (size_t)r * EE + i4 * 4);
            int key, rk;
            #define PUT(N_, C_, V_)                                             \
                key = (N_) * RR + r;                                            \
                rk  = atomicAdd(&counts[key], 1);                               \
                if (rk < CAP) edges[(size_t)key * CAP + rk] =                   \
                    make_int2((C_), __float_as_int(V_));                        \
                else { int o = atomicAdd(ovfh, 1);                              \
                       if (o < OVCAP) ovf[o] = make_int4(key, (C_),             \
                                                __float_as_int(V_), 0); }
            PUT(rw.x, cl.x, vl.x)
            PUT(rw.y, cl.y, vl.y)
            PUT(rw.z, cl.z, vl.z)
            PUT(rw.w, cl.w, vl.w)
            #undef PUT
        }
    }
}

__device__ __forceinline__ void accum_chunks(float a0[8], float a1[8], float v,
                                             shortx8 c0, shortx8 c1) {
    #pragma unroll
    for (int j = 0; j < 8; j++) {
        a0[j] = fmaf(v, bf2f((unsigned short)c0[j]), a0[j]);
        a1[j] = fmaf(v, bf2f((unsigned short)c1[j]), a1[j]);
    }
}

// Fused layer v4 (bucket-CSR). 256 threads = 4 waves, 64-node tile, grid 782, LDS 16.6 KB.
// Bucket addresses are computed, not loaded: chain depth 1 (edge->emb only).
// phaseA(r): issue meta(r+1) [bucket int4 x2 + cnt], issue emb23(r), fma e0..e3
//            (0-padded), rare tail (deg>4), overflow scan, pack -> Bt.
// phaseB(r): issue emb01(r+1) under MFMA(r); A-frags stream from L2-resident Tf.
template<bool FINAL>
__global__ __launch_bounds__(256, 3)
void layer_k(const unsigned short* __restrict__ embIn,
             const unsigned short* __restrict__ Tf,
             const int* __restrict__ counts,
             const int2* __restrict__ eg,
             const int* __restrict__ ovfh,
             const int4* __restrict__ ovf,
             unsigned short* __restrict__ embOut,
             float* __restrict__ outF)
{
    __shared__ __align__(16) unsigned short Bt[64 * 128];   // 16 KB
    __shared__ float ssred[4][64];

    const int t    = threadIdx.x;
    const int lane = t & 63;
    const int w    = t >> 6;      // 0..3: i block (x32)
    const int colq = lane & 15;
    const int q    = lane >> 4;
    const int n0   = blockIdx.x * NT;
    const int nsub = t >> 3;      // node within pass (0..31)
    const int dgrp = t & 7;       // dim chunks dgrp, dgrp+8

    const int  nId[2] = { n0 + nsub, n0 + 32 + nsub };
    const bool okp[2] = { nId[0] < NE, nId[1] < NE };
    const int  kb[2]  = { (okp[0] ? nId[0] : 0) * RR, (okp[1] ? nId[1] : 0) * RR };

    int ovfn = ovfh[0];
    if (ovfn > OVCAP) ovfn = OVCAP;
    if (ovfn < 0) ovfn = 0;

    floatx4 acc[2][4];
    #pragma unroll
    for (int a = 0; a < 2; a++)
        #pragma unroll
        for (int c = 0; c < 4; c++)
            acc[a][c] = (floatx4){0.f, 0.f, 0.f, 0.f};

    // pipeline state for relation r (current) — meta + emb01 rows
    int4 eaC[2], ebC[2];      // bucket slots 0-3: {c0,v0,c1,v1},{c2,v2,c3,v3}
    int  cntC[2];
    shortx8 m[2][2][2];       // emb rows for e0,e1: [p][edge][chunk]

    #pragma unroll
    for (int p = 0; p < 2; p++) {        // prologue: meta(0) + emb01(0)
        const int4* bkt = (const int4*)(eg + (size_t)(kb[p] + 0) * CAP);
        eaC[p] = bkt[0];
        ebC[p] = bkt[1];
        cntC[p] = counts[kb[p] + 0];
    }
    #pragma unroll
    for (int p = 0; p < 2; p++) {
        const unsigned short* r0 = embIn + (size_t)eaC[p].x * DD + dgrp * 8;
        const unsigned short* r1 = embIn + (size_t)eaC[p].z * DD + dgrp * 8;
        m[p][0][0] = *(const shortx8*)r0;
        m[p][0][1] = *(const shortx8*)(r0 + 64);
        m[p][1][0] = *(const shortx8*)r1;
        m[p][1][1] = *(const shortx8*)(r1 + 64);
    }

    #pragma unroll 1
    for (int r = 0; r < RR; r++) {
        // ---- issue meta(r+1)
        int4 eaN[2], ebN[2];
        int  cntN[2];
        if (r + 1 < RR) {
            #pragma unroll
            for (int p = 0; p < 2; p++) {
                const int4* bkt = (const int4*)(eg + (size_t)(kb[p] + r + 1) * CAP);
                eaN[p] = bkt[0];
                ebN[p] = bkt[1];
                cntN[p] = counts[kb[p] + r + 1];
            }
        }
        // ---- issue emb23(r) (0-padded cols are harmless broadcast loads)
        shortx8 e23[2][2][2];
        #pragma unroll
        for (int p = 0; p < 2; p++) {
            const unsigned short* r2 = embIn + (size_t)ebC[p].x * DD + dgrp * 8;
            const unsigned short* r3 = embIn + (size_t)ebC[p].z * DD + dgrp * 8;
            e23[p][0][0] = *(const shortx8*)r2;
            e23[p][0][1] = *(const shortx8*)(r2 + 64);
            e23[p][1][0] = *(const shortx8*)r3;
            e23[p][1][1] = *(const shortx8*)(r3 + 64);
        }
        // ---- phase A: accumulate + pack -> Bt
        #pragma unroll
        for (int p = 0; p < 2; p++) {
            float a0[8], a1[8];
            #pragma unroll
            for (int j = 0; j < 8; j++) { a0[j] = 0.f; a1[j] = 0.f; }
            float v0 = okp[p] ? __int_as_float(eaC[p].y) : 0.f;
            float v1 = okp[p] ? __int_as_float(eaC[p].w) : 0.f;
            float v2 = okp[p] ? __int_as_float(ebC[p].y) : 0.f;
            float v3 = okp[p] ? __int_as_float(ebC[p].w) : 0.f;
            accum_chunks(a0, a1, v0, m[p][0][0], m[p][0][1]);
            accum_chunks(a0, a1, v1, m[p][1][0], m[p][1][1]);
            accum_chunks(a0, a1, v2, e23[p][0][0], e23[p][0][1]);
            accum_chunks(a0, a1, v3, e23[p][1][0], e23[p][1][1]);
            int cc = okp[p] ? cntC[p] : 0;
            if (cc > 4) {                               // rare: deg > 4
                int ce = cc < CAP ? cc : CAP;
                const int2* b2 = eg + (size_t)(kb[p] + r) * CAP;
                #pragma unroll 1
                for (int k = 4; k < ce; k++) {
                    int2 E = b2[k];
                    float v = __int_as_float(E.y);
                    const unsigned short* rw_ = embIn + (size_t)E.x * DD + dgrp * 8;
                    accum_chunks(a0, a1, v, *(const shortx8*)rw_, *(const shortx8*)(rw_ + 64));
                }
            }
            if (ovfn) {                                 // global overflow (expect ~1 entry)
                int myKey = okp[p] ? kb[p] + r : -1;
                #pragma unroll 1
                for (int i = 0; i < ovfn; i++) {
                    int4 o = ovf[i];
                    if (o.x == myKey) {
                        float v = __int_as_float(o.z);
                        const unsigned short* rw_ = embIn + (size_t)o.y * DD + dgrp * 8;
                        accum_chunks(a0, a1, v, *(const shortx8*)rw_, *(const shortx8*)(rw_ + 64));
                    }
                }
            }
            int nl = p * 32 + nsub;
            shortx8 w0, w1;
            #pragma unroll
            for (int j = 0; j < 8; j++) { w0[j] = (short)f2bf(a0[j]); w1[j] = (short)f2bf(a1[j]); }
            int pc = (dgrp ^ nl) & 7;
            *(shortx8*)&Bt[nl * 128 + pc * 8] = w0;
            *(shortx8*)&Bt[nl * 128 + (8 | pc) * 8] = w1;
        }
        __syncthreads();   // Bt(r) ready

        // ---- phase B: issue emb01(r+1) under MFMA(r)
        if (r + 1 < RR) {
            #pragma unroll
            for (int p = 0; p < 2; p++) {
                const unsigned short* r0 = embIn + (size_t)eaN[p].x * DD + dgrp * 8;
                const unsigned short* r1 = embIn + (size_t)eaN[p].z * DD + dgrp * 8;
                m[p][0][0] = *(const shortx8*)r0;
                m[p][0][1] = *(const shortx8*)(r0 + 64);
                m[p][1][0] = *(const shortx8*)r1;
                m[p][1][1] = *(const shortx8*)(r1 + 64);
                eaC[p] = eaN[p]; ebC[p] = ebN[p]; cntC[p] = cntN[p];
            }
        }
        shortx8 afN[2];
        #pragma unroll
        for (int it2 = 0; it2 < 2; it2++)
            afN[it2] = *(const shortx8*)(Tf + ((((size_t)r * 8 + (w * 2 + it2)) * 4 + 0) * 64 + lane) * 8);
        #pragma unroll 1
        for (int kt = 0; kt < 4; kt++) {
            shortx8 afC[2];
            afC[0] = afN[0]; afC[1] = afN[1];
            if (kt < 3) {
                #pragma unroll
                for (int it2 = 0; it2 < 2; it2++)
                    afN[it2] = *(const shortx8*)(Tf + ((((size_t)r * 8 + (w * 2 + it2)) * 4 + (kt + 1)) * 64 + lane) * 8);
            }
            int lc = kt * 4 + q;
            shortx8 bfr[4];
            #pragma unroll
            for (int c = 0; c < 4; c++) {
                int nl = c * 16 + colq;
                int pc = (lc & 8) | ((lc ^ nl) & 7);
                bfr[c] = *(const shortx8*)&Bt[nl * 128 + pc * 8];
            }
            #pragma unroll
            for (int it2 = 0; it2 < 2; it2++)
                #pragma unroll
                for (int c = 0; c < 4; c++)
                    acc[it2][c] = __builtin_amdgcn_mfma_f32_16x16x32_bf16(afC[it2], bfr[c], acc[it2][c], 0, 0, 0);
        }
        __syncthreads();   // MFMA done with Bt
    }

    // ---- epilogue. D: col=lane&15 -> n, row=q*4+g -> i (within 16x16 tile)
    if (!FINAL) {
        #pragma unroll
        for (int c = 0; c < 4; c++) {
            int n = n0 + c * 16 + colq;
            if (n < NE) {
                #pragma unroll
                for (int it2 = 0; it2 < 2; it2++) {
                    shortx4 wv;
                    #pragma unroll
                    for (int g = 0; g < 4; g++) {
                        float v = acc[it2][c][g];
                        v = v > 0.f ? v : 0.f;
                        wv[g] = (short)f2bf(v);
                    }
                    *(shortx4*)(embOut + ((size_t)n * DD + w * 32 + it2 * 16 + q * 4)) = wv;
                }
            }
        }
    } else {
        #pragma unroll
        for (int c = 0; c < 4; c++) {
            float ss = 0.f;
            #pragma unroll
            for (int it2 = 0; it2 < 2; it2++)
                #pragma unroll
                for (int g = 0; g < 4; g++) {
                    float v = acc[it2][c][g];
                    v = v > 0.f ? v : 0.f;
                    acc[it2][c][g] = v;
                    ss += v * v;
                }
            ss += __shfl_xor(ss, 16, 64);   // reduce over q quads
            ss += __shfl_xor(ss, 32, 64);
            if (q == 0) ssred[w][c * 16 + colq] = ss;
        }
        __syncthreads();
        #pragma unroll
        for (int c = 0; c < 4; c++) {
            int nl = c * 16 + colq;
            float tot = ssred[0][nl] + ssred[1][nl] + ssred[2][nl] + ssred[3][nl];
            float scale = 1.f / fmaxf(sqrtf(tot), 1e-12f);
            int n = n0 + nl;
            if (n < NE) {
                #pragma unroll
                for (int it2 = 0; it2 < 2; it2++) {
                    floatx4 v4;
                    #pragma unroll
                    for (int g = 0; g < 4; g++) v4[g] = acc[it2][c][g] * scale;
                    *(floatx4*)(outF + ((size_t)n * DD + w * 32 + it2 * 16 + q * 4)) = v4;
                }
            }
        }
    }
}

static inline size_t align256(size_t x) { return (x + 255) & ~(size_t)255; }

extern "C" void kernel_launch(void* const* d_in, const int* in_sizes, int n_in,
                              void* d_out, int out_size, void* d_ws, size_t ws_size,
                              hipStream_t stream)
{
    const float* ent_emb   = (const float*)d_in[0];   // [NE, DD] fp32
    const float* rel_trans = (const float*)d_in[1];   // [RR, DD, DD] fp32
    const float* edge_val  = (const float*)d_in[2];   // [RR, EE] fp32
    const int*   edge_row  = (const int*)d_in[3];     // [RR, EE] int32
    const int*   edge_col  = (const int*)d_in[4];     // [RR, EE] int32
    float* out = (float*)d_out;                       // [NE, DD] fp32

    char* ws = (char*)d_ws;
    size_t off = 0;
    int*  counts = (int*)(ws + off);  off = align256(off + (size_t)NTOT * 4);   // 3.2 MB
    int*  ovfh   = (int*)(ws + off);  off = align256(off + 256);
    int4* ovf    = (int4*)(ws + off); off = align256(off + (size_t)OVCAP * 16); // 1 MB
    int2* edges  = (int2*)(ws + off); off = align256(off + (size_t)NTOT * CAP * 8); // 51.2 MB
    size_t zspan = off;               // memset counts..edges in one shot
    unsigned short* Tf   = (unsigned short*)(ws + off); off = align256(off + (size_t)RR * DD * DD * 2);
    unsigned short* embA = (unsigned short*)(ws + off); off = align256(off + (size_t)NE * DD * 2);
    unsigned short* embB = (unsigned short*)(ws + off); off = align256(off + (size_t)NE * DD * 2);
    // total ~82 MB

    hipMemsetAsync(ws, 0, zspan, stream);
    prep_k<<<TB + EB + FB, 256, 0, stream>>>(rel_trans, Tf, (const float4*)ent_emb,
                                             (shortx4*)embA, edge_row, edge_col, edge_val,
                                             counts, ovfh, ovf, edges);
    int nb = (NE + NT - 1) / NT;  // 782
    layer_k<false><<<nb, 256, 0, stream>>>(embA, Tf, counts, edges, ovfh, ovf, embB, nullptr);
    layer_k<true ><<<nb, 256, 0, stream>>>(embB, Tf, counts, edges, ovfh, ovf, nullptr, out);
}

// Round 8
// 445.366 us; speedup vs baseline: 1.1587x; 1.1587x over previous
//
#include <hip/hip_runtime.h>
#include <stdint.h>

#define NE 50000   // entities
#define DD 128     // dim
#define RR 16      // relations
#define EE 50000   // edges per relation
#define NT 32      // nodes per block
#define RC 4       // relations per K-chunk
#define KC (RC * DD)          // 512 K per chunk
#define NTOT (RR * NE)        // 800000 (node,rel) keys, node-major
#define CAP 8                 // bucket capacity: one 64B line per key
#define OVCAP 4096            // overflow capacity (expect ~1 entry)

typedef short  shortx8 __attribute__((ext_vector_type(8)));
typedef short  shortx4 __attribute__((ext_vector_type(4)));
typedef float  floatx4 __attribute__((ext_vector_type(4)));

__device__ __forceinline__ unsigned short f2bf(float f) {
    unsigned u = __float_as_uint(f);
    u += 0x7fffu + ((u >> 16) & 1u);   // RNE
    return (unsigned short)(u >> 16);
}
__device__ __forceinline__ float bf2f(unsigned short h) {
    return __uint_as_float(((unsigned)h) << 16);
}

// ---- single preprocessing kernel:
//  seg T: rel_trans -> MFMA-fragment-ordered bf16 Tf
//  seg E: ent_emb fp32 -> bf16
//  seg F: edge -> bucket edges[key*8+rank] via atomic rank (1 edge/thread);
//         buckets NOT pre-zeroed -- layer masks slots by counts.
// Tf: element T[r][row][k] at ((((r*8+(row>>4))*4+(k>>5))*64) + ((k>>3)&3)*16 + (row&15))*8 + (k&7)
#define TB 128
#define EB 6250
#define FB 3125
__global__ void prep_k(const float* __restrict__ rt, unsigned short* __restrict__ Tf,
                       const float4* __restrict__ emb, shortx4* __restrict__ embA,
                       const int* __restrict__ erow, const int* __restrict__ ecol,
                       const float* __restrict__ eval,
                       int* __restrict__ counts, int* __restrict__ ovfh,
                       int4* __restrict__ ovf, int2* __restrict__ edges) {
    int b = blockIdx.x, t = threadIdx.x;
    if (b < TB) {
        int c = b * 256 + t;                 // chunk: 8 consecutive k of one (r,row)
        int r = c >> 11, row = (c >> 4) & 127, cb = c & 15;
        int kt = cb >> 2, qq = cb & 3, rg = row >> 4, m = row & 15;
        const float4* src = (const float4*)(rt + (size_t)c * 8);
        float4 v0 = src[0], v1 = src[1];
        shortx8 w;
        w[0] = (short)f2bf(v0.x); w[1] = (short)f2bf(v0.y);
        w[2] = (short)f2bf(v0.z); w[3] = (short)f2bf(v0.w);
        w[4] = (short)f2bf(v1.x); w[5] = (short)f2bf(v1.y);
        w[6] = (short)f2bf(v1.z); w[7] = (short)f2bf(v1.w);
        size_t idx = ((((size_t)r * 8 + rg) * 4 + kt) * 64 + qq * 16 + m) * 8;
        *(shortx8*)(Tf + idx) = w;
    } else if (b < TB + EB) {
        int i = (b - TB) * 256 + t;
        if (i < NE * DD / 4) {
            float4 v = emb[i];
            shortx4 w;
            w[0] = (short)f2bf(v.x); w[1] = (short)f2bf(v.y);
            w[2] = (short)f2bf(v.z); w[3] = (short)f2bf(v.w);
            embA[i] = w;
        }
    } else {
        int e = (b - TB - EB) * 256 + t;
        if (e < RR * EE) {
            int r = e / EE;
            int i = e - r * EE;
            int  row = erow[(size_t)r * EE + i];
            int  col = ecol[(size_t)r * EE + i];
            float vl = eval[(size_t)r * EE + i];
            int key = row * RR + r;
            int rk  = atomicAdd(&counts[key], 1);
            if (rk < CAP) edges[(size_t)key * CAP + rk] = make_int2(col, __float_as_int(vl));
            else {
                int o = atomicAdd(ovfh, 1);
                if (o < OVCAP) ovf[o] = make_int4(key, col, __float_as_int(vl), 0);
            }
        }
    }
}

__device__ __forceinline__ void accum16(float a[16], float v, shortx8 c0, shortx8 c1) {
    #pragma unroll
    for (int j = 0; j < 8; j++) {
        a[j]     = fmaf(v, bf2f((unsigned short)c0[j]), a[j]);
        a[j + 8] = fmaf(v, bf2f((unsigned short)c1[j]), a[j + 8]);
    }
}

// Fused layer v5 (K-chunked, bucket-CSR). 256 threads = 4 waves, 32-node tile, grid 1563.
// Per chunk (4 relations): preload 4 rounds' bucket meta (computable addrs, independent);
// 4 gather rounds (thread = one (node,rel) key x 16 dims; 8-lane group reads a full
// 256B emb row coalesced) -> swizzled Bcat LDS; ONE barrier; MFMA over K=512 with
// A-frags streamed from fragment-ordered Tf (L2); ONE barrier. 8 barriers total.
template<bool FINAL>
__global__ __launch_bounds__(256, 3)
void layer_k(const unsigned short* __restrict__ embIn,
             const unsigned short* __restrict__ Tf,
             const int* __restrict__ counts,
             const int2* __restrict__ eg,
             const int* __restrict__ ovfh,
             const int4* __restrict__ ovf,
             unsigned short* __restrict__ embOut,
             float* __restrict__ outF)
{
    __shared__ __align__(16) unsigned short Bc[NT * KC];   // 32 KB
    __shared__ float ssred[4][NT];

    const int t    = threadIdx.x;
    const int lane = t & 63;
    const int w    = t >> 6;      // wave: i rows w*32..+32
    const int colq = lane & 15;
    const int q    = lane >> 4;
    const int n0   = blockIdx.x * NT;
    const int kg   = t >> 3;      // 0..31: node within tile
    const int dt   = t & 7;       // dim group (16 dims)

    const bool ok      = (n0 + kg) < NE;
    const int  keyBase = (ok ? (n0 + kg) : 0) * RR;

    int ovfn = ovfh[0];
    ovfn = ovfn < 0 ? 0 : (ovfn > OVCAP ? OVCAP : ovfn);

    floatx4 acc[2][2];
    #pragma unroll
    for (int a = 0; a < 2; a++)
        #pragma unroll
        for (int c = 0; c < 2; c++)
            acc[a][c] = (floatx4){0.f, 0.f, 0.f, 0.f};

    #pragma unroll 1
    for (int rc = 0; rc < RR / RC; rc++) {
        // ---- preload bucket meta for all RC rounds (independent computable addrs)
        int4 eaA[RC], ebA[RC];
        int  ccA[RC];
        #pragma unroll
        for (int j = 0; j < RC; j++) {
            int key = keyBase + rc * RC + j;
            const int4* bkt = (const int4*)(eg + (size_t)key * CAP);
            eaA[j] = bkt[0];
            ebA[j] = bkt[1];
            ccA[j] = counts[key];
        }
        // ---- gather rounds (no barriers between)
        #pragma unroll 1
        for (int j = 0; j < RC; j++) {
            int cc = ok ? ccA[j] : 0;
            int   c0 = cc > 0 ? eaA[j].x : 0;
            float v0 = cc > 0 ? __int_as_float(eaA[j].y) : 0.f;
            int   c1 = cc > 1 ? eaA[j].z : 0;
            float v1 = cc > 1 ? __int_as_float(eaA[j].w) : 0.f;
            int   c2 = cc > 2 ? ebA[j].x : 0;
            float v2 = cc > 2 ? __int_as_float(ebA[j].y) : 0.f;
            int   c3 = cc > 3 ? ebA[j].z : 0;
            float v3 = cc > 3 ? __int_as_float(ebA[j].w) : 0.f;
            const unsigned short* p0 = embIn + (size_t)c0 * DD + dt * 16;
            const unsigned short* p1 = embIn + (size_t)c1 * DD + dt * 16;
            const unsigned short* p2 = embIn + (size_t)c2 * DD + dt * 16;
            const unsigned short* p3 = embIn + (size_t)c3 * DD + dt * 16;
            shortx8 u00 = ((const shortx8*)p0)[0], u01 = ((const shortx8*)p0)[1];
            shortx8 u10 = ((const shortx8*)p1)[0], u11 = ((const shortx8*)p1)[1];
            shortx8 u20 = ((const shortx8*)p2)[0], u21 = ((const shortx8*)p2)[1];
            shortx8 u30 = ((const shortx8*)p3)[0], u31 = ((const shortx8*)p3)[1];
            float a[16];
            #pragma unroll
            for (int d = 0; d < 16; d++) a[d] = 0.f;
            accum16(a, v0, u00, u01);
            accum16(a, v1, u10, u11);
            accum16(a, v2, u20, u21);
            accum16(a, v3, u30, u31);
            if (cc > 4) {                              // rare: deg > 4
                int key = keyBase + rc * RC + j;
                int ce = cc < CAP ? cc : CAP;
                const int2* b2 = eg + (size_t)key * CAP;
                #pragma unroll 1
                for (int k = 4; k < ce; k++) {
                    int2 E = b2[k];
                    const unsigned short* pp = embIn + (size_t)E.x * DD + dt * 16;
                    accum16(a, __int_as_float(E.y), ((const shortx8*)pp)[0], ((const shortx8*)pp)[1]);
                }
            }
            if (ovfn) {                                // global overflow (expect ~1 entry)
                int myKey = ok ? keyBase + rc * RC + j : -1;
                #pragma unroll 1
                for (int i = 0; i < ovfn; i++) {
                    int4 o = ovf[i];
                    if (o.x == myKey) {
                        const unsigned short* pp = embIn + (size_t)o.y * DD + dt * 16;
                        accum16(a, __int_as_float(o.z), ((const shortx8*)pp)[0], ((const shortx8*)pp)[1]);
                    }
                }
            }
            shortx8 w0, w1;
            #pragma unroll
            for (int d = 0; d < 8; d++) { w0[d] = (short)f2bf(a[d]); w1[d] = (short)f2bf(a[d + 8]); }
            int cA  = j * 16 + dt * 2;                 // chunk index within 512-K row
            int pcA = (cA & ~7) | ((cA ^ kg) & 7);
            int cB  = cA + 1;
            int pcB = (cB & ~7) | ((cB ^ kg) & 7);
            *(shortx8*)&Bc[kg * KC + pcA * 8] = w0;
            *(shortx8*)&Bc[kg * KC + pcB * 8] = w1;
        }
        __syncthreads();   // Bcat(chunk) ready

        // ---- MFMA over K=512: A from Tf (1-kt prefetch), B from Bc
        const int rBase = rc * RC;
        shortx8 afN[2];
        #pragma unroll
        for (int it2 = 0; it2 < 2; it2++)
            afN[it2] = *(const shortx8*)(Tf + ((((size_t)rBase * 8 + (w * 2 + it2)) * 4 + 0) * 64 + lane) * 8);
        #pragma unroll 1
        for (int kt = 0; kt < 16; kt++) {
            shortx8 afC[2];
            afC[0] = afN[0]; afC[1] = afN[1];
            if (kt < 15) {
                int kn  = kt + 1;
                int rr2 = rBase + (kn >> 2);
                int ktl = kn & 3;
                #pragma unroll
                for (int it2 = 0; it2 < 2; it2++)
                    afN[it2] = *(const shortx8*)(Tf + ((((size_t)rr2 * 8 + (w * 2 + it2)) * 4 + ktl) * 64 + lane) * 8);
            }
            int cI = kt * 4 + q;
            shortx8 bfr[2];
            #pragma unroll
            for (int c = 0; c < 2; c++) {
                int nl = c * 16 + colq;
                int pc = (cI & ~7) | ((cI ^ nl) & 7);
                bfr[c] = *(const shortx8*)&Bc[nl * KC + pc * 8];
            }
            #pragma unroll
            for (int it2 = 0; it2 < 2; it2++)
                #pragma unroll
                for (int c = 0; c < 2; c++)
                    acc[it2][c] = __builtin_amdgcn_mfma_f32_16x16x32_bf16(afC[it2], bfr[c], acc[it2][c], 0, 0, 0);
        }
        __syncthreads();   // MFMA done with Bc
    }

    // ---- epilogue. D: col=lane&15 -> n, row=q*4+g -> i (within 16x16 tile)
    if (!FINAL) {
        #pragma unroll
        for (int c = 0; c < 2; c++) {
            int n = n0 + c * 16 + colq;
            if (n < NE) {
                #pragma unroll
                for (int it2 = 0; it2 < 2; it2++) {
                    shortx4 wv;
                    #pragma unroll
                    for (int g = 0; g < 4; g++) {
                        float v = acc[it2][c][g];
                        v = v > 0.f ? v : 0.f;
                        wv[g] = (short)f2bf(v);
                    }
                    *(shortx4*)(embOut + ((size_t)n * DD + w * 32 + it2 * 16 + q * 4)) = wv;
                }
            }
        }
    } else {
        #pragma unroll
        for (int c = 0; c < 2; c++) {
            float ss = 0.f;
            #pragma unroll
            for (int it2 = 0; it2 < 2; it2++)
                #pragma unroll
                for (int g = 0; g < 4; g++) {
                    float v = acc[it2][c][g];
                    v = v > 0.f ? v : 0.f;
                    acc[it2][c][g] = v;
                    ss += v * v;
                }
            ss += __shfl_xor(ss, 16, 64);   // reduce over q quads
            ss += __shfl_xor(ss, 32, 64);
            if (q == 0) ssred[w][c * 16 + colq] = ss;
        }
        __syncthreads();
        #pragma unroll
        for (int c = 0; c < 2; c++) {
            int nl = c * 16 + colq;
            float tot = ssred[0][nl] + ssred[1][nl] + ssred[2][nl] + ssred[3][nl];
            float scale = 1.f / fmaxf(sqrtf(tot), 1e-12f);
            int n = n0 + nl;
            if (n < NE) {
                #pragma unroll
                for (int it2 = 0; it2 < 2; it2++) {
                    floatx4 v4;
                    #pragma unroll
                    for (int g = 0; g < 4; g++) v4[g] = acc[it2][c][g] * scale;
                    *(floatx4*)(outF + ((size_t)n * DD + w * 32 + it2 * 16 + q * 4)) = v4;
                }
            }
        }
    }
}

static inline size_t align256(size_t x) { return (x + 255) & ~(size_t)255; }

extern "C" void kernel_launch(void* const* d_in, const int* in_sizes, int n_in,
                              void* d_out, int out_size, void* d_ws, size_t ws_size,
                              hipStream_t stream)
{
    const float* ent_emb   = (const float*)d_in[0];   // [NE, DD] fp32
    const float* rel_trans = (const float*)d_in[1];   // [RR, DD, DD] fp32
    const float* edge_val  = (const float*)d_in[2];   // [RR, EE] fp32
    const int*   edge_row  = (const int*)d_in[3];     // [RR, EE] int32
    const int*   edge_col  = (const int*)d_in[4];     // [RR, EE] int32
    float* out = (float*)d_out;                       // [NE, DD] fp32

    char* ws = (char*)d_ws;
    size_t off = 0;
    int*  counts = (int*)(ws + off);  off = align256(off + (size_t)NTOT * 4);   // 3.2 MB
    int*  ovfh   = (int*)(ws + off);  off = align256(off + 256);
    size_t zspan = off;               // memset counts + ovfh only
    int4* ovf    = (int4*)(ws + off); off = align256(off + (size_t)OVCAP * 16);
    int2* edges  = (int2*)(ws + off); off = align256(off + (size_t)NTOT * CAP * 8); // 51.2 MB (NOT zeroed)
    unsigned short* Tf   = (unsigned short*)(ws + off); off = align256(off + (size_t)RR * DD * DD * 2);
    unsigned short* embA = (unsigned short*)(ws + off); off = align256(off + (size_t)NE * DD * 2);
    unsigned short* embB = (unsigned short*)(ws + off); off = align256(off + (size_t)NE * DD * 2);
    // total ~82 MB

    hipMemsetAsync(ws, 0, zspan, stream);
    prep_k<<<TB + EB + FB, 256, 0, stream>>>(rel_trans, Tf, (const float4*)ent_emb,
                                             (shortx4*)embA, edge_row, edge_col, edge_val,
                                             counts, ovfh, ovf, edges);
    int nb = (NE + NT - 1) / NT;  // 1563
    layer_k<false><<<nb, 256, 0, stream>>>(embA, Tf, counts, edges, ovfh, ovf, embB, nullptr);
    layer_k<true ><<<nb, 256, 0, stream>>>(embB, Tf, counts, edges, ovfh, ovf, nullptr, out);
}

// Round 9
// 329.245 us; speedup vs baseline: 1.5674x; 1.3527x over previous
//
#include <hip/hip_runtime.h>
#include <stdint.h>

#define NE 50000   // entities
#define DD 128     // dim
#define RR 16      // relations
#define EE 50000   // edges per relation
#define NT 32      // nodes per block
#define RC 4       // relations per K-chunk
#define KC (RC * DD)          // 512 K per chunk
#define NTOT (RR * NE)        // 800000 (node,rel) keys, node-major
#define CAP 8                 // bucket capacity: one 64B line per key
#define OVCAP 4096            // overflow capacity (expect ~1 entry)

typedef short  shortx8 __attribute__((ext_vector_type(8)));
typedef short  shortx4 __attribute__((ext_vector_type(4)));
typedef float  floatx4 __attribute__((ext_vector_type(4)));

__device__ __forceinline__ unsigned short f2bf(float f) {
    unsigned u = __float_as_uint(f);
    u += 0x7fffu + ((u >> 16) & 1u);   // RNE
    return (unsigned short)(u >> 16);
}
__device__ __forceinline__ float bf2f(unsigned short h) {
    return __uint_as_float(((unsigned)h) << 16);
}

// ---- single preprocessing kernel:
//  seg T: rel_trans -> MFMA-fragment-ordered bf16 Tf
//  seg E: ent_emb fp32 -> bf16
//  seg F: edge -> bucket edges[key*8+rank] via atomic rank (1 edge/thread);
//         buckets NOT pre-zeroed -- layer masks slots by counts.
// Tf: element T[r][row][k] at ((((r*8+(row>>4))*4+(k>>5))*64) + ((k>>3)&3)*16 + (row&15))*8 + (k&7)
#define TB 128
#define EB 6250
#define FB 3125
__global__ void prep_k(const float* __restrict__ rt, unsigned short* __restrict__ Tf,
                       const float4* __restrict__ emb, shortx4* __restrict__ embA,
                       const int* __restrict__ erow, const int* __restrict__ ecol,
                       const float* __restrict__ eval,
                       int* __restrict__ counts, int* __restrict__ ovfh,
                       int4* __restrict__ ovf, int2* __restrict__ edges) {
    int b = blockIdx.x, t = threadIdx.x;
    if (b < TB) {
        int c = b * 256 + t;                 // chunk: 8 consecutive k of one (r,row)
        int r = c >> 11, row = (c >> 4) & 127, cb = c & 15;
        int kt = cb >> 2, qq = cb & 3, rg = row >> 4, m = row & 15;
        const float4* src = (const float4*)(rt + (size_t)c * 8);
        float4 v0 = src[0], v1 = src[1];
        shortx8 w;
        w[0] = (short)f2bf(v0.x); w[1] = (short)f2bf(v0.y);
        w[2] = (short)f2bf(v0.z); w[3] = (short)f2bf(v0.w);
        w[4] = (short)f2bf(v1.x); w[5] = (short)f2bf(v1.y);
        w[6] = (short)f2bf(v1.z); w[7] = (short)f2bf(v1.w);
        size_t idx = ((((size_t)r * 8 + rg) * 4 + kt) * 64 + qq * 16 + m) * 8;
        *(shortx8*)(Tf + idx) = w;
    } else if (b < TB + EB) {
        int i = (b - TB) * 256 + t;
        if (i < NE * DD / 4) {
            float4 v = emb[i];
            shortx4 w;
            w[0] = (short)f2bf(v.x); w[1] = (short)f2bf(v.y);
            w[2] = (short)f2bf(v.z); w[3] = (short)f2bf(v.w);
            embA[i] = w;
        }
    } else {
        int e = (b - TB - EB) * 256 + t;
        if (e < RR * EE) {
            int r = e / EE;
            int i = e - r * EE;
            int  row = erow[(size_t)r * EE + i];
            int  col = ecol[(size_t)r * EE + i];
            float vl = eval[(size_t)r * EE + i];
            int key = row * RR + r;
            int rk  = atomicAdd(&counts[key], 1);
            if (rk < CAP) edges[(size_t)key * CAP + rk] = make_int2(col, __float_as_int(vl));
            else {
                int o = atomicAdd(ovfh, 1);
                if (o < OVCAP) ovf[o] = make_int4(key, col, __float_as_int(vl), 0);
            }
        }
    }
}

__device__ __forceinline__ void accum16(float a[16], float v, shortx8 c0, shortx8 c1) {
    #pragma unroll
    for (int j = 0; j < 8; j++) {
        a[j]     = fmaf(v, bf2f((unsigned short)c0[j]), a[j]);
        a[j + 8] = fmaf(v, bf2f((unsigned short)c1[j]), a[j + 8]);
    }
}

// Fused layer v5b (K-chunked, bucket-CSR). 256 threads = 4 waves, 32-node tile, grid 1563.
// Per chunk (4 relations): meta + 4 gather rounds FULLY UNROLLED (static indexing --
// R8's `#pragma unroll 1` made eaA[j] runtime-indexed => scratch spill, 212 MB WRITE).
// thread = one (node,rel) key x 16 dims; 8-lane group reads a full 256B emb row
// coalesced -> swizzled Bc LDS; ONE barrier; MFMA over K=512 with A-frags streamed
// from fragment-ordered Tf (L2); ONE barrier. 8 barriers total per block.
template<bool FINAL>
__global__ __launch_bounds__(256, 3)
void layer_k(const unsigned short* __restrict__ embIn,
             const unsigned short* __restrict__ Tf,
             const int* __restrict__ counts,
             const int2* __restrict__ eg,
             const int* __restrict__ ovfh,
             const int4* __restrict__ ovf,
             unsigned short* __restrict__ embOut,
             float* __restrict__ outF)
{
    __shared__ __align__(16) unsigned short Bc[NT * KC];   // 32 KB
    __shared__ float ssred[4][NT];

    const int t    = threadIdx.x;
    const int lane = t & 63;
    const int w    = t >> 6;      // wave: i rows w*32..+32
    const int colq = lane & 15;
    const int q    = lane >> 4;
    const int n0   = blockIdx.x * NT;
    const int kg   = t >> 3;      // 0..31: node within tile
    const int dt   = t & 7;       // dim group (16 dims)

    const bool ok      = (n0 + kg) < NE;
    const int  keyBase = (ok ? (n0 + kg) : 0) * RR;

    int ovfn = ovfh[0];
    ovfn = ovfn < 0 ? 0 : (ovfn > OVCAP ? OVCAP : ovfn);

    floatx4 acc[2][2];
    #pragma unroll
    for (int a = 0; a < 2; a++)
        #pragma unroll
        for (int c = 0; c < 2; c++)
            acc[a][c] = (floatx4){0.f, 0.f, 0.f, 0.f};

    #pragma unroll 1
    for (int rc = 0; rc < RR / RC; rc++) {
        // ---- preload bucket meta for all RC rounds (independent computable addrs)
        int4 eaA[RC], ebA[RC];
        int  ccA[RC];
        #pragma unroll
        for (int j = 0; j < RC; j++) {
            int key = keyBase + rc * RC + j;
            const int4* bkt = (const int4*)(eg + (size_t)key * CAP);
            eaA[j] = bkt[0];
            ebA[j] = bkt[1];
            ccA[j] = counts[key];
        }
        // ---- gather rounds: FULL unroll => all private arrays statically indexed
        #pragma unroll
        for (int j = 0; j < RC; j++) {
            int cc = ok ? ccA[j] : 0;
            int   c0 = cc > 0 ? eaA[j].x : 0;
            float v0 = cc > 0 ? __int_as_float(eaA[j].y) : 0.f;
            int   c1 = cc > 1 ? eaA[j].z : 0;
            float v1 = cc > 1 ? __int_as_float(eaA[j].w) : 0.f;
            int   c2 = cc > 2 ? ebA[j].x : 0;
            float v2 = cc > 2 ? __int_as_float(ebA[j].y) : 0.f;
            int   c3 = cc > 3 ? ebA[j].z : 0;
            float v3 = cc > 3 ? __int_as_float(ebA[j].w) : 0.f;
            const unsigned short* p0 = embIn + (size_t)c0 * DD + dt * 16;
            const unsigned short* p1 = embIn + (size_t)c1 * DD + dt * 16;
            const unsigned short* p2 = embIn + (size_t)c2 * DD + dt * 16;
            const unsigned short* p3 = embIn + (size_t)c3 * DD + dt * 16;
            shortx8 u00 = ((const shortx8*)p0)[0], u01 = ((const shortx8*)p0)[1];
            shortx8 u10 = ((const shortx8*)p1)[0], u11 = ((const shortx8*)p1)[1];
            shortx8 u20 = ((const shortx8*)p2)[0], u21 = ((const shortx8*)p2)[1];
            shortx8 u30 = ((const shortx8*)p3)[0], u31 = ((const shortx8*)p3)[1];
            float a[16];
            #pragma unroll
            for (int d = 0; d < 16; d++) a[d] = 0.f;
            accum16(a, v0, u00, u01);
            accum16(a, v1, u10, u11);
            accum16(a, v2, u20, u21);
            accum16(a, v3, u30, u31);
            if (cc > 4) {                              // rare: deg > 4
                int key = keyBase + rc * RC + j;
                int ce = cc < CAP ? cc : CAP;
                const int2* b2 = eg + (size_t)key * CAP;
                #pragma unroll 1
                for (int k = 4; k < ce; k++) {
                    int2 E = b2[k];
                    const unsigned short* pp = embIn + (size_t)E.x * DD + dt * 16;
                    accum16(a, __int_as_float(E.y), ((const shortx8*)pp)[0], ((const shortx8*)pp)[1]);
                }
            }
            if (ovfn) {                                // global overflow (expect ~1 entry)
                int myKey = ok ? keyBase + rc * RC + j : -1;
                #pragma unroll 1
                for (int i = 0; i < ovfn; i++) {
                    int4 o = ovf[i];
                    if (o.x == myKey) {
                        const unsigned short* pp = embIn + (size_t)o.y * DD + dt * 16;
                        accum16(a, __int_as_float(o.z), ((const shortx8*)pp)[0], ((const shortx8*)pp)[1]);
                    }
                }
            }
            shortx8 w0, w1;
            #pragma unroll
            for (int d = 0; d < 8; d++) { w0[d] = (short)f2bf(a[d]); w1[d] = (short)f2bf(a[d + 8]); }
            int cA  = j * 16 + dt * 2;                 // chunk index within 512-K row
            int pcA = (cA & ~7) | ((cA ^ kg) & 7);
            int cB  = cA + 1;
            int pcB = (cB & ~7) | ((cB ^ kg) & 7);
            *(shortx8*)&Bc[kg * KC + pcA * 8] = w0;
            *(shortx8*)&Bc[kg * KC + pcB * 8] = w1;
        }
        __syncthreads();   // Bc(chunk) ready

        // ---- MFMA over K=512: A from Tf (1-kt prefetch), B from Bc
        const int rBase = rc * RC;
        shortx8 afN[2];
        #pragma unroll
        for (int it2 = 0; it2 < 2; it2++)
            afN[it2] = *(const shortx8*)(Tf + ((((size_t)rBase * 8 + (w * 2 + it2)) * 4 + 0) * 64 + lane) * 8);
        #pragma unroll 1
        for (int kt = 0; kt < 16; kt++) {
            shortx8 afC[2];
            afC[0] = afN[0]; afC[1] = afN[1];
            if (kt < 15) {
                int kn  = kt + 1;
                int rr2 = rBase + (kn >> 2);
                int ktl = kn & 3;
                #pragma unroll
                for (int it2 = 0; it2 < 2; it2++)
                    afN[it2] = *(const shortx8*)(Tf + ((((size_t)rr2 * 8 + (w * 2 + it2)) * 4 + ktl) * 64 + lane) * 8);
            }
            int cI = kt * 4 + q;
            shortx8 bfr[2];
            #pragma unroll
            for (int c = 0; c < 2; c++) {
                int nl = c * 16 + colq;
                int pc = (cI & ~7) | ((cI ^ nl) & 7);
                bfr[c] = *(const shortx8*)&Bc[nl * KC + pc * 8];
            }
            #pragma unroll
            for (int it2 = 0; it2 < 2; it2++)
                #pragma unroll
                for (int c = 0; c < 2; c++)
                    acc[it2][c] = __builtin_amdgcn_mfma_f32_16x16x32_bf16(afC[it2], bfr[c], acc[it2][c], 0, 0, 0);
        }
        __syncthreads();   // MFMA done with Bc
    }

    // ---- epilogue. D: col=lane&15 -> n, row=q*4+g -> i (within 16x16 tile)
    if (!FINAL) {
        #pragma unroll
        for (int c = 0; c < 2; c++) {
            int n = n0 + c * 16 + colq;
            if (n < NE) {
                #pragma unroll
                for (int it2 = 0; it2 < 2; it2++) {
                    shortx4 wv;
                    #pragma unroll
                    for (int g = 0; g < 4; g++) {
                        float v = acc[it2][c][g];
                        v = v > 0.f ? v : 0.f;
                        wv[g] = (short)f2bf(v);
                    }
                    *(shortx4*)(embOut + ((size_t)n * DD + w * 32 + it2 * 16 + q * 4)) = wv;
                }
            }
        }
    } else {
        #pragma unroll
        for (int c = 0; c < 2; c++) {
            float ss = 0.f;
            #pragma unroll
            for (int it2 = 0; it2 < 2; it2++)
                #pragma unroll
                for (int g = 0; g < 4; g++) {
                    float v = acc[it2][c][g];
                    v = v > 0.f ? v : 0.f;
                    acc[it2][c][g] = v;
                    ss += v * v;
                }
            ss += __shfl_xor(ss, 16, 64);   // reduce over q quads
            ss += __shfl_xor(ss, 32, 64);
            if (q == 0) ssred[w][c * 16 + colq] = ss;
        }
        __syncthreads();
        #pragma unroll
        for (int c = 0; c < 2; c++) {
            int nl = c * 16 + colq;
            float tot = ssred[0][nl] + ssred[1][nl] + ssred[2][nl] + ssred[3][nl];
            float scale = 1.f / fmaxf(sqrtf(tot), 1e-12f);
            int n = n0 + nl;
            if (n < NE) {
                #pragma unroll
                for (int it2 = 0; it2 < 2; it2++) {
                    floatx4 v4;
                    #pragma unroll
                    for (int g = 0; g < 4; g++) v4[g] = acc[it2][c][g] * scale;
                    *(floatx4*)(outF + ((size_t)n * DD + w * 32 + it2 * 16 + q * 4)) = v4;
                }
            }
        }
    }
}

static inline size_t align256(size_t x) { return (x + 255) & ~(size_t)255; }

extern "C" void kernel_launch(void* const* d_in, const int* in_sizes, int n_in,
                              void* d_out, int out_size, void* d_ws, size_t ws_size,
                              hipStream_t stream)
{
    const float* ent_emb   = (const float*)d_in[0];   // [NE, DD] fp32
    const float* rel_trans = (const float*)d_in[1];   // [RR, DD, DD] fp32
    const float* edge_val  = (const float*)d_in[2];   // [RR, EE] fp32
    const int*   edge_row  = (const int*)d_in[3];     // [RR, EE] int32
    const int*   edge_col  = (const int*)d_in[4];     // [RR, EE] int32
    float* out = (float*)d_out;                       // [NE, DD] fp32

    char* ws = (char*)d_ws;
    size_t off = 0;
    int*  counts = (int*)(ws + off);  off = align256(off + (size_t)NTOT * 4);   // 3.2 MB
    int*  ovfh   = (int*)(ws + off);  off = align256(off + 256);
    size_t zspan = off;               // memset counts + ovfh only
    int4* ovf    = (int4*)(ws + off); off = align256(off + (size_t)OVCAP * 16);
    int2* edges  = (int2*)(ws + off); off = align256(off + (size_t)NTOT * CAP * 8); // 51.2 MB (NOT zeroed)
    unsigned short* Tf   = (unsigned short*)(ws + off); off = align256(off + (size_t)RR * DD * DD * 2);
    unsigned short* embA = (unsigned short*)(ws + off); off = align256(off + (size_t)NE * DD * 2);
    unsigned short* embB = (unsigned short*)(ws + off); off = align256(off + (size_t)NE * DD * 2);
    // total ~82 MB

    hipMemsetAsync(ws, 0, zspan, stream);
    prep_k<<<TB + EB + FB, 256, 0, stream>>>(rel_trans, Tf, (const float4*)ent_emb,
                                             (shortx4*)embA, edge_row, edge_col, edge_val,
                                             counts, ovfh, ovf, edges);
    int nb = (NE + NT - 1) / NT;  // 1563
    layer_k<false><<<nb, 256, 0, stream>>>(embA, Tf, counts, edges, ovfh, ovf, embB, nullptr);
    layer_k<true ><<<nb, 256, 0, stream>>>(embB, Tf, counts, edges, ovfh, ovf, nullptr, out);
}